// Round 11
// baseline (299.518 us; speedup 1.0000x reference)
//
#include <hip/hip_runtime.h>
#include <hip/hip_bf16.h>
#include <cstdint>
#include <cstddef>

// out[B,OUT] = (x * alpha) @ W,  W[i,o] = exp(-||col_i - row_o||^2)
// B=8192, IN=4096, OUT=4096.  f32 in/out.
//
// k0 (fused prep): x f32 -> bf16 Xb ; Wt[o][i] = alpha[i]*exp(-d2) bf16 (B^T)
// k1: 256x256 GEMM, BK=64, 8 waves (2M x 4N) -- r5's schedule (best measured:
//     235us, 52.7% MfmaUtil) with the MFMA shape switched 16x16x32 ->
//     32x32x16: halves MFMA instruction count (512->256/tile) and cuts the
//     matrix-pipe backlog 2483->2066 cy/tile (ubench 2382 vs 2075 TF).  LDS
//     layout, staging, vmcnt cadence, phase structure ALL unchanged from r5.
//
// Phase skeleton (1 barrier/phase): STAGE(unit); vmcnt(6); s_barrier;
//   sched_barrier; ds_reads(this phase); setprio(1); 8 MFMA; setprio(0).
// Quadrants: p0 = mb01 x nb0 (reads A-unit0 + B-unit0), p1 = mb01 x nb1
//   (reads B-unit1), p2 = mb23 x nb0 (reads A-unit1), p3 = mb23 x nb1 (reg
//   only).  Stage cadence A0,B0,B1,A1 @ p0..p3, each vmcnt(6): every unit is
//   staged 3-4 phases before its confirm, confirmed >=1 barrier before first
//   read (RAW); overwrites >=4 barriers after last read (WAR); floor 6 in
//   flight (verified in r5, raced clean across all replays).
// Fragment layout 32x32x16: A/B lane l -> row/col l&31, k=(l>>5)*8+0..7
//   (contiguous bf16x8 = 1 ds_read_b128, same as the verified 16x16 pattern);
//   C/D col=lane&31, row=(reg&3)+8*(reg>>2)+4*(lane>>5)  [guide m74/m101].
// LDS: unit = [128 rows][64 k]; 16B chunk kc of row rho stored at
//   kc ^ (rho&7); staging pre-swizzles the per-lane GLOBAL address (LDS dest
//   linear); fragment reads spread 8 lanes per 4-bank group = conflict-free
//   (measured 0 since r5).

#define IN_DIM  4096
#define OUT_DIM 4096
#define BATCH   8192

#define BM 256
#define BN 256
#define BK 64
#define KTILES (IN_DIM / BK)   // 64
#define THREADS 512

#define UNIT   8192            // elems per stage unit (128 rows * 64)
#define OPOFF  16384           // A (2 units) -> B offset
#define BUFOFF 32768           // elems per buffer (A + B)

#define NCONV  (BATCH * IN_DIM / (256 * 8))   // 16384 convert blocks
#define NWTB   (OUT_DIM * 2)                  // 8192 wt blocks

typedef __bf16 bf16x8  __attribute__((ext_vector_type(8)));
typedef float  f32x16  __attribute__((ext_vector_type(16)));

// ---------------------------------------------------------------------------
// Fused prep: blocks [0,NCONV) convert x; blocks [NCONV, NCONV+NWTB) build Wt.
// ---------------------------------------------------------------------------
__global__ __launch_bounds__(256) void prep_kernel(
    const float* __restrict__ x,
    const float* __restrict__ rows_mean,     // [OUT,2]
    const float* __restrict__ columns_mean,  // [IN,2]
    const float* __restrict__ alpha,         // [IN]
    __bf16* __restrict__ xb,                 // [BATCH][IN]
    __bf16* __restrict__ Wt)                 // [OUT][IN]
{
    const int b = blockIdx.x;
    if (b < NCONV) {
        const size_t i = ((size_t)b * 256 + threadIdx.x) * 8;
        const float4 v0 = *(const float4*)(x + i);
        const float4 v1 = *(const float4*)(x + i + 4);
        bf16x8 o;
        o[0] = (__bf16)v0.x; o[1] = (__bf16)v0.y; o[2] = (__bf16)v0.z; o[3] = (__bf16)v0.w;
        o[4] = (__bf16)v1.x; o[5] = (__bf16)v1.y; o[6] = (__bf16)v1.z; o[7] = (__bf16)v1.w;
        *(bf16x8*)(xb + i) = o;
    } else {
        const int bb = b - NCONV;
        const int o  = bb >> 1;
        const int i0 = ((bb & 1) * 256 + threadIdx.x) * 8;

        const float r0 = rows_mean[2 * o];
        const float r1 = rows_mean[2 * o + 1];

        const float4* cm = (const float4*)(columns_mean + 2 * (size_t)i0);
        float4 c01 = cm[0], c23 = cm[1], c45 = cm[2], c67 = cm[3];
        const float4* ap = (const float4*)(alpha + i0);
        float4 a0 = ap[0], a1 = ap[1];

        float cx[8] = {c01.x, c01.z, c23.x, c23.z, c45.x, c45.z, c67.x, c67.z};
        float cy[8] = {c01.y, c01.w, c23.y, c23.w, c45.y, c45.w, c67.y, c67.w};
        float av[8] = {a0.x, a0.y, a0.z, a0.w, a1.x, a1.y, a1.z, a1.w};

        bf16x8 w;
#pragma unroll
        for (int j = 0; j < 8; ++j) {
            float d0 = cx[j] - r0;
            float d1 = cy[j] - r1;
            w[j] = (__bf16)(__expf(-(d0 * d0 + d1 * d1)) * av[j]);
        }
        *(bf16x8*)(Wt + (size_t)o * IN_DIM + i0) = w;
    }
}

// ---------------------------------------------------------------------------
__global__ __launch_bounds__(THREADS, 2) void gemm_kernel(
    const __bf16* __restrict__ Xb,   // [BATCH, IN] bf16
    const __bf16* __restrict__ Wt,   // [OUT][IN]   bf16 (B^T)
    float* __restrict__ Out)         // [BATCH, OUT]
{
    __shared__ __align__(16) __bf16 lds[2 * BUFOFF];   // 128 KiB

    const int tid  = threadIdx.x;
    const int wave = tid >> 6;
    const int lane = tid & 63;
    const int lr32 = lane & 31;          // row/col within 32-fragment
    const int h8   = lane >> 5;          // k-half selector (0/1)
    const int wm   = wave >> 2;          // 0..1  (M waves)
    const int wn   = wave & 3;           // 0..3  (N waves)

    // ---- XCD-aware block swizzle (512 wg, 512%8==0) ----
    const int swz  = (blockIdx.x & 7) * 64 + (blockIdx.x >> 3);
    const int m0   = (swz >> 4) * BM;
    const int n0   = (swz & 15) * BN;

    // ---- staging precompute (2 loads/thread per unit) -- unchanged from r5 ----
    const __bf16 *pA[2], *pB[2];
    __bf16 *lA[2], *lB[2];
#pragma unroll
    for (int j = 0; j < 2; ++j) {
        const int c  = wave * 64 + lane + j * 512;
        const int rp = c >> 3;
        const int kg = (c & 7) ^ (rp & 7);
        const int rA = ((rp >> 6) & 1) * 128 + (rp & 63);
        const int rB = (rp >> 5) * 64 + (rp & 31);
        pA[j] = Xb + (size_t)(m0 + rA) * IN_DIM + kg * 8;
        pB[j] = Wt + (size_t)(n0 + rB) * IN_DIM + kg * 8;
        lA[j] = lds + j * 4096 + wave * 512;          // wave-uniform dest
        lB[j] = lds + OPOFF + j * 4096 + wave * 512;
    }

    auto STAGE_A = [&](int kt, int h, int b) {
#pragma unroll
        for (int j = 0; j < 2; ++j)
            __builtin_amdgcn_global_load_lds(
                (const __attribute__((address_space(1))) unsigned int*)
                    (pA[j] + (size_t)h * 64 * IN_DIM + kt * BK),
                (__attribute__((address_space(3))) unsigned int*)
                    (lA[j] + b * BUFOFF + h * UNIT), 16, 0, 0);
    };
    auto STAGE_B = [&](int kt, int h, int b) {
#pragma unroll
        for (int j = 0; j < 2; ++j)
            __builtin_amdgcn_global_load_lds(
                (const __attribute__((address_space(1))) unsigned int*)
                    (pB[j] + (size_t)h * 32 * IN_DIM + kt * BK),
                (__attribute__((address_space(3))) unsigned int*)
                    (lB[j] + b * BUFOFF + h * UNIT), 16, 0, 0);
    };

    // ---- fragment read bases (32x32 shape) ----
    // A: global row g = wm*128 + mb*32 + lr32 -> unit mb>>1,
    //    row-in-unit rho = wm*64 + (mb&1)*32 + lr32   (rho&7 == lr32&7)
    // B: global col g = wn*64 + nb*32 + lr32 -> unit nb, rho = wn*32 + lr32
    // logical 16B chunk (ks*2 + h8), phys = logical ^ (lr32&7)
    int scx[4];
#pragma unroll
    for (int ks = 0; ks < 4; ++ks)
        scx[ks] = (((ks * 2 + h8) ^ (lr32 & 7)) << 3);   // elem offset in row

    const __bf16* aB32 = lds + (wm * 64 + lr32) * 64;
    const __bf16* bB32 = lds + OPOFF + (wn * 32 + lr32) * 64;

    auto RD_A = [&](int mb, int ks, int bo) -> bf16x8 {
        return *(const bf16x8*)(aB32 + bo + (mb >> 1) * UNIT + (mb & 1) * 2048
                                + scx[ks]);
    };
    auto RD_B = [&](int nb, int ks, int bo) -> bf16x8 {
        return *(const bf16x8*)(bB32 + bo + nb * UNIT + scx[ks]);
    };

    f32x16 acc[4][2];
#pragma unroll
    for (int m = 0; m < 4; ++m)
#pragma unroll
        for (int n = 0; n < 2; ++n)
            acc[m][n] = (f32x16)(0.f);

    // ---- prologue: tile 0 (4 units) -> buf0 ----
    STAGE_A(0, 0, 0); STAGE_B(0, 0, 0); STAGE_B(0, 1, 0); STAGE_A(0, 1, 0);
    asm volatile("s_waitcnt vmcnt(0)" ::: "memory");
    __builtin_amdgcn_s_barrier();

    bf16x8 afL[2][4], afH[2][4], bL[4], bH[4];

    for (int t = 0; t < KTILES; ++t) {
        const int bo  = (t & 1) * BUFOFF;
        const int sb  = (t & 1) ^ 1;
        const int kt1 = (t + 1 < KTILES) ? t + 1 : KTILES - 1;  // clamp benign

        // ===== p0: mb01 x nb0 (A-unit0, B-unit0); stage A0(t+1) =====
        STAGE_A(kt1, 0, sb);
        asm volatile("s_waitcnt vmcnt(6)" ::: "memory");
        __builtin_amdgcn_s_barrier();
        __builtin_amdgcn_sched_barrier(0);
#pragma unroll
        for (int ks = 0; ks < 4; ++ks) {
            bL[ks]     = RD_B(0, ks, bo);
            afL[0][ks] = RD_A(0, ks, bo);
            afL[1][ks] = RD_A(1, ks, bo);
        }
        __builtin_amdgcn_s_setprio(1);
#pragma unroll
        for (int ks = 0; ks < 4; ++ks)
#pragma unroll
            for (int mb = 0; mb < 2; ++mb)
                acc[mb][0] = __builtin_amdgcn_mfma_f32_32x32x16_bf16(
                    afL[mb][ks], bL[ks], acc[mb][0], 0, 0, 0);
        __builtin_amdgcn_s_setprio(0);

        // ===== p1: mb01 x nb1 (B-unit1); stage B0(t+1) =====
        STAGE_B(kt1, 0, sb);
        asm volatile("s_waitcnt vmcnt(6)" ::: "memory");
        __builtin_amdgcn_s_barrier();
        __builtin_amdgcn_sched_barrier(0);
#pragma unroll
        for (int ks = 0; ks < 4; ++ks)
            bH[ks] = RD_B(1, ks, bo);
        __builtin_amdgcn_s_setprio(1);
#pragma unroll
        for (int ks = 0; ks < 4; ++ks)
#pragma unroll
            for (int mb = 0; mb < 2; ++mb)
                acc[mb][1] = __builtin_amdgcn_mfma_f32_32x32x16_bf16(
                    afL[mb][ks], bH[ks], acc[mb][1], 0, 0, 0);
        __builtin_amdgcn_s_setprio(0);

        // ===== p2: mb23 x nb0 (A-unit1); stage B1(t+1) =====
        STAGE_B(kt1, 1, sb);
        asm volatile("s_waitcnt vmcnt(6)" ::: "memory");
        __builtin_amdgcn_s_barrier();
        __builtin_amdgcn_sched_barrier(0);
#pragma unroll
        for (int ks = 0; ks < 4; ++ks) {
            afH[0][ks] = RD_A(2, ks, bo);
            afH[1][ks] = RD_A(3, ks, bo);
        }
        __builtin_amdgcn_s_setprio(1);
#pragma unroll
        for (int ks = 0; ks < 4; ++ks)
#pragma unroll
            for (int mb = 0; mb < 2; ++mb)
                acc[2 + mb][0] = __builtin_amdgcn_mfma_f32_32x32x16_bf16(
                    afH[mb][ks], bL[ks], acc[2 + mb][0], 0, 0, 0);
        __builtin_amdgcn_s_setprio(0);

        // ===== p3: mb23 x nb1 (reg-only); stage A1(t+1) =====
        STAGE_A(kt1, 1, sb);
        asm volatile("s_waitcnt vmcnt(6)" ::: "memory");
        __builtin_amdgcn_s_barrier();
        __builtin_amdgcn_s_setprio(1);
#pragma unroll
        for (int ks = 0; ks < 4; ++ks)
#pragma unroll
            for (int mb = 0; mb < 2; ++mb)
                acc[2 + mb][1] = __builtin_amdgcn_mfma_f32_32x32x16_bf16(
                    afH[mb][ks], bH[ks], acc[2 + mb][1], 0, 0, 0);
        __builtin_amdgcn_s_setprio(0);
    }

    // ---- epilogue: 32x32 C/D: col=lane&31, row=(reg&3)+8*(reg>>2)+4*(lane>>5) ----
    const int crow = m0 + wm * 128 + h8 * 4;
    const int ccol = n0 + wn * 64 + lr32;
#pragma unroll
    for (int mb = 0; mb < 4; ++mb)
#pragma unroll
        for (int nb = 0; nb < 2; ++nb) {
            float* o = Out + (size_t)(crow + mb * 32) * OUT_DIM + (ccol + nb * 32);
#pragma unroll
            for (int j = 0; j < 16; ++j)
                o[(size_t)((j & 3) + 8 * (j >> 2)) * OUT_DIM] = acc[mb][nb][j];
        }
}

// ---------------------------------------------------------------------------
extern "C" void kernel_launch(void* const* d_in, const int* in_sizes, int n_in,
                              void* d_out, int out_size, void* d_ws, size_t ws_size,
                              hipStream_t stream) {
    const float* x  = (const float*)d_in[0];   // [8192, 4096]
    const float* rm = (const float*)d_in[1];   // [4096, 2]
    const float* cm = (const float*)d_in[2];   // [4096, 2]
    const float* al = (const float*)d_in[3];   // [4096]
    float* out = (float*)d_out;                // [8192, 4096]

    __bf16* Wt = (__bf16*)d_ws;                                     // 32 MiB
    __bf16* Xb = (__bf16*)((char*)d_ws + (size_t)32 * 1024 * 1024); // 64 MiB

    prep_kernel<<<NCONV + NWTB, 256, 0, stream>>>(x, rm, cm, al, Xb, Wt);

    dim3 g2((BATCH / BM) * (OUT_DIM / BN));    // 512
    gemm_kernel<<<g2, THREADS, 0, stream>>>(Xb, Wt, out);
}

// Round 12
// 262.722 us; speedup vs baseline: 1.1401x; 1.1401x over previous
//
#include <hip/hip_runtime.h>
#include <hip/hip_bf16.h>
#include <cstdint>
#include <cstddef>

// out[B,OUT] = (x * alpha) @ W,  W[i,o] = exp(-||col_i - row_o||^2)
// B=8192, IN=4096, OUT=4096.  f32 in/out.
//
// k0 (fused prep): x f32 -> bf16 Xb ; Wt[o][i] = alpha[i]*exp(-d2) bf16 (B^T)
// k1: 256x256 GEMM, BK=64, 8 waves (2M x 4N), 16x16x32 MFMA (r5 shape/layout;
//     r11's 32x32 attempt regressed w/ bank conflicts).  NEW this round: the
//     untested m201 ingredient combo -- reads issued at phase START (drain
//     during the barrier wait, overlapped with other waves' previous MFMA
//     cluster) + ZERO-STALL vmcnt plan + r5's 1-barrier/phase skeleton.
//     r7 had reads-early but a 1-phase-old vmcnt (latency trap); r10 had the
//     zero-stall plan but reads-after-barrier + hard lgkm drain.
//
// Phase (quadrants p0..p3 of tile t):
//   p0: read bL,afL (12 ds); stage A0+B0(t+1); vmcnt(6); bar; MFMA afL*bL
//   p1: read bH (4 ds);      stage B1(t+1);    vmcnt(6); bar; MFMA afL*bH
//   p2: read afH (8 ds);     stage A1(t+1);              bar; MFMA afH*bL
//   p3: (no reads)                             vmcnt(4); bar; MFMA afH*bH
// No sched_barrier / lgkmcnt(0): compiler's counted lgkm waits gate each MFMA
// and may interleave reads with adjacent MFMA clusters (desired).
// Wait algebra (outstanding FIFO): after p3(t-1): {B1(t),A1(t)}=4; p0 +4 ->8,
//   vmcnt(6) confirms B1(t) [staged p1(t-1), 3ph, landed]; p1 +2 ->8, vmcnt(6)
//   confirms A1(t) [p2(t-1), 3ph]; p2 +2 ->8; p3 vmcnt(4) confirms A0,B0(t+1)
//   [p0(t), 3ph].  RAW: each phase's reads protected by prev phase's wait +
//   barrier.  WAR: every stage overwrites a slot last read >=4 barriers prior
//   (write-land bounded by the confirming vmcnt+barrier before next read).
//   Floor 4 in flight -- never drains.  Tail clamp benign; trailing vmcnt(0).
// LDS layout (0 conflicts since r5): unit=[128 rows][64 k]; 16B chunk kc of
// row rho stored at kc ^ (rho&7); staging pre-swizzles per-lane GLOBAL addr
// (LDS dest linear per gload_lds rule).

#define IN_DIM  4096
#define OUT_DIM 4096
#define BATCH   8192

#define BM 256
#define BN 256
#define BK 64
#define KTILES (IN_DIM / BK)   // 64
#define THREADS 512

#define UNIT   8192            // elems per stage unit (128 rows * 64)
#define OPOFF  16384           // A (2 units) -> B offset
#define BUFOFF 32768           // elems per buffer (A + B)

#define NCONV  (BATCH * IN_DIM / (256 * 8))   // 16384 convert blocks
#define NWTB   (OUT_DIM * 2)                  // 8192 wt blocks

typedef __bf16 bf16x8 __attribute__((ext_vector_type(8)));
typedef float  f32x4  __attribute__((ext_vector_type(4)));

// ---------------------------------------------------------------------------
// Fused prep: blocks [0,NCONV) convert x; blocks [NCONV, NCONV+NWTB) build Wt.
// ---------------------------------------------------------------------------
__global__ __launch_bounds__(256) void prep_kernel(
    const float* __restrict__ x,
    const float* __restrict__ rows_mean,     // [OUT,2]
    const float* __restrict__ columns_mean,  // [IN,2]
    const float* __restrict__ alpha,         // [IN]
    __bf16* __restrict__ xb,                 // [BATCH][IN]
    __bf16* __restrict__ Wt)                 // [OUT][IN]
{
    const int b = blockIdx.x;
    if (b < NCONV) {
        const size_t i = ((size_t)b * 256 + threadIdx.x) * 8;
        const float4 v0 = *(const float4*)(x + i);
        const float4 v1 = *(const float4*)(x + i + 4);
        bf16x8 o;
        o[0] = (__bf16)v0.x; o[1] = (__bf16)v0.y; o[2] = (__bf16)v0.z; o[3] = (__bf16)v0.w;
        o[4] = (__bf16)v1.x; o[5] = (__bf16)v1.y; o[6] = (__bf16)v1.z; o[7] = (__bf16)v1.w;
        *(bf16x8*)(xb + i) = o;
    } else {
        const int bb = b - NCONV;
        const int o  = bb >> 1;
        const int i0 = ((bb & 1) * 256 + threadIdx.x) * 8;

        const float r0 = rows_mean[2 * o];
        const float r1 = rows_mean[2 * o + 1];

        const float4* cm = (const float4*)(columns_mean + 2 * (size_t)i0);
        float4 c01 = cm[0], c23 = cm[1], c45 = cm[2], c67 = cm[3];
        const float4* ap = (const float4*)(alpha + i0);
        float4 a0 = ap[0], a1 = ap[1];

        float cx[8] = {c01.x, c01.z, c23.x, c23.z, c45.x, c45.z, c67.x, c67.z};
        float cy[8] = {c01.y, c01.w, c23.y, c23.w, c45.y, c45.w, c67.y, c67.w};
        float av[8] = {a0.x, a0.y, a0.z, a0.w, a1.x, a1.y, a1.z, a1.w};

        bf16x8 w;
#pragma unroll
        for (int j = 0; j < 8; ++j) {
            float d0 = cx[j] - r0;
            float d1 = cy[j] - r1;
            w[j] = (__bf16)(__expf(-(d0 * d0 + d1 * d1)) * av[j]);
        }
        *(bf16x8*)(Wt + (size_t)o * IN_DIM + i0) = w;
    }
}

// ---------------------------------------------------------------------------
__global__ __launch_bounds__(THREADS, 2) void gemm_kernel(
    const __bf16* __restrict__ Xb,   // [BATCH, IN] bf16
    const __bf16* __restrict__ Wt,   // [OUT][IN]   bf16 (B^T)
    float* __restrict__ Out)         // [BATCH, OUT]
{
    __shared__ __align__(16) __bf16 lds[2 * BUFOFF];   // 128 KiB

    const int tid  = threadIdx.x;
    const int wave = tid >> 6;
    const int lane = tid & 63;
    const int lh   = lane >> 4;          // 0..3
    const int lr   = lane & 15;
    const int wm   = wave >> 2;          // 0..1  (M waves)
    const int wn   = wave & 3;           // 0..3  (N waves)

    // ---- XCD-aware block swizzle (512 wg, 512%8==0) ----
    const int swz  = (blockIdx.x & 7) * 64 + (blockIdx.x >> 3);
    const int m0   = (swz >> 4) * BM;
    const int n0   = (swz & 15) * BN;

    // ---- staging precompute (2 loads/thread per unit) ----
    const __bf16 *pA[2], *pB[2];
    __bf16 *lA[2], *lB[2];
#pragma unroll
    for (int j = 0; j < 2; ++j) {
        const int c  = wave * 64 + lane + j * 512;
        const int rp = c >> 3;
        const int kg = (c & 7) ^ (rp & 7);
        const int rA = ((rp >> 6) & 1) * 128 + (rp & 63);
        const int rB = (rp >> 5) * 64 + (rp & 31);
        pA[j] = Xb + (size_t)(m0 + rA) * IN_DIM + kg * 8;
        pB[j] = Wt + (size_t)(n0 + rB) * IN_DIM + kg * 8;
        lA[j] = lds + j * 4096 + wave * 512;          // wave-uniform dest
        lB[j] = lds + OPOFF + j * 4096 + wave * 512;
    }

    auto STAGE_A = [&](int kt, int h, int b) {
#pragma unroll
        for (int j = 0; j < 2; ++j)
            __builtin_amdgcn_global_load_lds(
                (const __attribute__((address_space(1))) unsigned int*)
                    (pA[j] + (size_t)h * 64 * IN_DIM + kt * BK),
                (__attribute__((address_space(3))) unsigned int*)
                    (lA[j] + b * BUFOFF + h * UNIT), 16, 0, 0);
    };
    auto STAGE_B = [&](int kt, int h, int b) {
#pragma unroll
        for (int j = 0; j < 2; ++j)
            __builtin_amdgcn_global_load_lds(
                (const __attribute__((address_space(1))) unsigned int*)
                    (pB[j] + (size_t)h * 32 * IN_DIM + kt * BK),
                (__attribute__((address_space(3))) unsigned int*)
                    (lB[j] + b * BUFOFF + h * UNIT), 16, 0, 0);
    };

    // ---- fragment read bases (swizzled chunks; rho&7 == lr&7) ----
    const int l7  = lr & 7;
    const int sc0 = lh ^ l7;          // kk=0 chunk
    const int sc1 = (4 + lh) ^ l7;    // kk=1 chunk
    const __bf16* aB = lds + (wm * 64 + lr) * 64;
    const __bf16* bB = lds + OPOFF + (wn * 32 + lr) * 64;

    auto RD_A = [&](int m, int kk, int bo) -> bf16x8 {
        return *(const bf16x8*)(aB + bo + (m >> 2) * UNIT + (m & 3) * 1024
                                + (kk ? sc1 : sc0) * 8);
    };
    auto RD_B = [&](int n, int kk, int bo) -> bf16x8 {
        return *(const bf16x8*)(bB + bo + (n >> 1) * UNIT + (n & 1) * 1024
                                + (kk ? sc1 : sc0) * 8);
    };

    f32x4 acc[8][4];
#pragma unroll
    for (int m = 0; m < 8; ++m)
#pragma unroll
        for (int n = 0; n < 4; ++n)
            acc[m][n] = f32x4{0.f, 0.f, 0.f, 0.f};

    // ---- prologue: tile 0 (4 units) -> buf0; confirm A0,B0(0) only ----
    STAGE_A(0, 0, 0); STAGE_B(0, 0, 0); STAGE_B(0, 1, 0); STAGE_A(0, 1, 0);
    asm volatile("s_waitcnt vmcnt(4)" ::: "memory");   // A0(0),B0(0) landed
    __builtin_amdgcn_s_barrier();

    for (int t = 0; t < KTILES; ++t) {
        const int bo  = (t & 1) * BUFOFF;
        const int sb  = (t & 1) ^ 1;
        const int kt1 = (t + 1 < KTILES) ? t + 1 : KTILES - 1;  // clamp benign

        bf16x8 afL[4][2], afH[4][2], bL[4], bH[4];

        // ===== p0: reads bL+afL FIRST; stage A0+B0(t+1); vmcnt(6); bar; MFMA =====
        bL[0] = RD_B(0, 0, bo); bL[1] = RD_B(0, 1, bo);
        bL[2] = RD_B(1, 0, bo); bL[3] = RD_B(1, 1, bo);
#pragma unroll
        for (int mf = 0; mf < 4; ++mf) {
            afL[mf][0] = RD_A(mf, 0, bo);
            afL[mf][1] = RD_A(mf, 1, bo);
        }
        STAGE_A(kt1, 0, sb);
        STAGE_B(kt1, 0, sb);
        asm volatile("s_waitcnt vmcnt(6)" ::: "memory");   // confirm B1(t)
        __builtin_amdgcn_s_barrier();
        __builtin_amdgcn_s_setprio(1);
#pragma unroll
        for (int kk = 0; kk < 2; ++kk)
#pragma unroll
            for (int mf = 0; mf < 4; ++mf)
#pragma unroll
                for (int nf = 0; nf < 2; ++nf)
                    acc[mf][nf] = __builtin_amdgcn_mfma_f32_16x16x32_bf16(
                        afL[mf][kk], bL[nf * 2 + kk], acc[mf][nf], 0, 0, 0);
        __builtin_amdgcn_s_setprio(0);

        // ===== p1: reads bH; stage B1(t+1); vmcnt(6); bar; MFMA =====
        bH[0] = RD_B(2, 0, bo); bH[1] = RD_B(2, 1, bo);
        bH[2] = RD_B(3, 0, bo); bH[3] = RD_B(3, 1, bo);
        STAGE_B(kt1, 1, sb);
        asm volatile("s_waitcnt vmcnt(6)" ::: "memory");   // confirm A1(t)
        __builtin_amdgcn_s_barrier();
        __builtin_amdgcn_s_setprio(1);
#pragma unroll
        for (int kk = 0; kk < 2; ++kk)
#pragma unroll
            for (int mf = 0; mf < 4; ++mf)
#pragma unroll
                for (int nf = 0; nf < 2; ++nf)
                    acc[mf][2 + nf] = __builtin_amdgcn_mfma_f32_16x16x32_bf16(
                        afL[mf][kk], bH[nf * 2 + kk], acc[mf][2 + nf], 0, 0, 0);
        __builtin_amdgcn_s_setprio(0);

        // ===== p2: reads afH; stage A1(t+1); no wait; bar; MFMA =====
#pragma unroll
        for (int mf = 0; mf < 4; ++mf) {
            afH[mf][0] = RD_A(4 + mf, 0, bo);
            afH[mf][1] = RD_A(4 + mf, 1, bo);
        }
        STAGE_A(kt1, 1, sb);
        __builtin_amdgcn_s_barrier();
        __builtin_amdgcn_s_setprio(1);
#pragma unroll
        for (int kk = 0; kk < 2; ++kk)
#pragma unroll
            for (int mf = 0; mf < 4; ++mf)
#pragma unroll
                for (int nf = 0; nf < 2; ++nf)
                    acc[4 + mf][nf] = __builtin_amdgcn_mfma_f32_16x16x32_bf16(
                        afH[mf][kk], bL[nf * 2 + kk], acc[4 + mf][nf], 0, 0, 0);
        __builtin_amdgcn_s_setprio(0);

        // ===== p3: no reads; vmcnt(4) [confirm A0,B0(t+1)]; bar; MFMA =====
        asm volatile("s_waitcnt vmcnt(4)" ::: "memory");
        __builtin_amdgcn_s_barrier();
        __builtin_amdgcn_s_setprio(1);
#pragma unroll
        for (int kk = 0; kk < 2; ++kk)
#pragma unroll
            for (int mf = 0; mf < 4; ++mf)
#pragma unroll
                for (int nf = 0; nf < 2; ++nf)
                    acc[4 + mf][2 + nf] = __builtin_amdgcn_mfma_f32_16x16x32_bf16(
                        afH[mf][kk], bH[nf * 2 + kk], acc[4 + mf][2 + nf], 0, 0, 0);
        __builtin_amdgcn_s_setprio(0);
    }

    // quiesce stray prefetches before CU hand-off
    asm volatile("s_waitcnt vmcnt(0)" ::: "memory");

    // ---- epilogue: C/D layout col=lane&15, row=(lane>>4)*4+j ----
    const int crow = m0 + wm * 128 + lh * 4;
    const int ccol = n0 + wn * 64 + lr;
#pragma unroll
    for (int m = 0; m < 8; ++m)
#pragma unroll
        for (int n = 0; n < 4; ++n) {
            float* o = Out + (size_t)(crow + m * 16) * OUT_DIM + (ccol + n * 16);
#pragma unroll
            for (int j = 0; j < 4; ++j)
                o[(size_t)j * OUT_DIM] = acc[m][n][j];
        }
}

// ---------------------------------------------------------------------------
extern "C" void kernel_launch(void* const* d_in, const int* in_sizes, int n_in,
                              void* d_out, int out_size, void* d_ws, size_t ws_size,
                              hipStream_t stream) {
    const float* x  = (const float*)d_in[0];   // [8192, 4096]
    const float* rm = (const float*)d_in[1];   // [4096, 2]
    const float* cm = (const float*)d_in[2];   // [4096, 2]
    const float* al = (const float*)d_in[3];   // [4096]
    float* out = (float*)d_out;                // [8192, 4096]

    __bf16* Wt = (__bf16*)d_ws;                                     // 32 MiB
    __bf16* Xb = (__bf16*)((char*)d_ws + (size_t)32 * 1024 * 1024); // 64 MiB

    prep_kernel<<<NCONV + NWTB, 256, 0, stream>>>(x, rm, cm, al, Xb, Wt);

    dim3 g2((BATCH / BM) * (OUT_DIM / BN));    // 512
    gemm_kernel<<<g2, THREADS, 0, stream>>>(Xb, Wt, out);
}